// Round 2
// baseline (345.355 us; speedup 1.0000x reference)
//
#include <hip/hip_runtime.h>
#include <hip/hip_bf16.h>

typedef unsigned short u16;
typedef short short8 __attribute__((ext_vector_type(8)));
typedef float f32x4 __attribute__((ext_vector_type(4)));

#define N_EMBD   1024
#define N_HEADS  16
#define HEAD_DIM 64
#define PRIV     48
#define SEQ_T    2048
#define BATCH    4
#define M_ROWS   (BATCH*SEQ_T)   // 8192
#define PNS      2816            // [share 16 | q 768 | k 768 | v 1024] = 2576 -> 11*256
#define NTILES   (SEQ_T/64)      // 32
#define NT_K     16              // K=1024 / BK=64

#if __has_builtin(__builtin_amdgcn_exp2f)
#define EXP2(x) __builtin_amdgcn_exp2f(x)
#else
#define EXP2(x) exp2f(x)
#endif

#if __has_builtin(__builtin_amdgcn_global_load_lds)
#define HAVE_GLL 1
#else
#define HAVE_GLL 0
#endif

__device__ __forceinline__ u16 f2bf(float f) {
  __hip_bfloat16 h = __float2bfloat16(f);
  return *reinterpret_cast<u16*>(&h);
}
__device__ __forceinline__ float bf2f(u16 s) {
  __hip_bfloat16 h;
  *reinterpret_cast<u16*>(&h) = s;
  return __bfloat162float(h);
}
__device__ __forceinline__ float loadv(const void* p, size_t i, int isf32) {
  return isf32 ? ((const float*)p)[i] : bf2f(((const u16*)p)[i]);
}
__device__ __forceinline__ u16 truncbf(float f) {
  unsigned u = __builtin_bit_cast(unsigned, f);
  return (u16)(u >> 16);
}
#if HAVE_GLL
__device__ __forceinline__ void gload_lds16(const u16* g, u16* l) {
  __builtin_amdgcn_global_load_lds(
      (const __attribute__((address_space(1))) void*)g,
      (__attribute__((address_space(3))) void*)l, 16, 0, 0);
}
#endif

// ---------------------------------------------------------------------------
// Dtype detector (1 = f32 inputs).
// ---------------------------------------------------------------------------
__global__ __launch_bounds__(256) void detect_kernel(const u16* __restrict__ x,
                                                     int* __restrict__ flag) {
  __shared__ int cnt;
  if (threadIdx.x == 0) cnt = 0;
  __syncthreads();
  u16 v = x[2 * threadIdx.x];
  int e = (v >> 7) & 0xFF;
  int junk = (e >= 0xC0 || (e != 0 && e <= 0x30)) ? 1 : 0;
  if (junk) atomicAdd(&cnt, 1);
  __syncthreads();
  if (threadIdx.x == 0) *flag = (cnt > 16) ? 1 : 0;
}

// ---------------------------------------------------------------------------
// Transposing pack (weights -> [n][k] bf16) + z=5 slice does zero-pad + biases.
// ---------------------------------------------------------------------------
__global__ __launch_bounds__(256) void pack_t_kernel(
    const void* __restrict__ Wsh, const void* __restrict__ Wq,
    const void* __restrict__ Wk,  const void* __restrict__ Wv,
    const void* __restrict__ Wo,
    const void* __restrict__ bsh, const void* __restrict__ bq,
    const void* __restrict__ bk,  const void* __restrict__ bv,
    const void* __restrict__ bo,
    u16* __restrict__ Wcat, u16* __restrict__ Woc,
    u16* __restrict__ bcat, u16* __restrict__ boc,
    const int* __restrict__ flagp)
{
  const int f = *flagp;
  if (blockIdx.z == 5) {  // pad + biases
    const int flat = blockIdx.y * 16 + blockIdx.x;
    const int padN = (PNS - 2576) * 1024;
    for (int i = flat * 256 + threadIdx.x; i < padN; i += 256 * 256)
      Wcat[(size_t)2576 * 1024 + i] = 0;
    if (flat == 0) {
      for (int c = threadIdx.x; c < PNS; c += 256) {
        float v = 0.f;
        if (c < 16)        v = loadv(bsh, c, f);
        else if (c < 784)  v = loadv(bq, c - 16, f);
        else if (c < 1552) v = loadv(bk, c - 784, f);
        else if (c < 2576) v = loadv(bv, c - 1552, f);
        bcat[c] = f2bf(v);
      }
    } else if (flat == 1) {
      for (int c = threadIdx.x; c < N_EMBD; c += 256)
        boc[c] = f2bf(loadv(bo, c, f));
    }
    return;
  }
  const void* src; u16* dst; int N, rowOff;
  switch (blockIdx.z) {
    case 0: src = Wsh; dst = Wcat; N = 16;   rowOff = 0;    break;
    case 1: src = Wq;  dst = Wcat; N = 768;  rowOff = 16;   break;
    case 2: src = Wk;  dst = Wcat; N = 768;  rowOff = 784;  break;
    case 3: src = Wv;  dst = Wcat; N = 1024; rowOff = 1552; break;
    default:src = Wo;  dst = Woc;  N = 1024; rowOff = 0;    break;
  }
  const int n0 = blockIdx.x * 64;
  if (n0 >= N) return;
  const int k0 = blockIdx.y * 64;
  __shared__ u16 t[64][65];
  const int tx = threadIdx.x & 63, ty = threadIdx.x >> 6;
#pragma unroll
  for (int rr = 0; rr < 16; rr++) {
    int k = k0 + ty * 16 + rr;
    int n = n0 + tx;
    float v = (n < N) ? loadv(src, (size_t)k * N + n, f) : 0.f;
    t[ty * 16 + rr][tx] = f2bf(v);
  }
  __syncthreads();
#pragma unroll
  for (int rr = 0; rr < 16; rr++) {
    int n = ty * 16 + rr;
    if (n0 + n < N)
      dst[(size_t)(rowOff + n0 + n) * 1024 + k0 + tx] = t[tx][n];
  }
}

// ---------------------------------------------------------------------------
// x (f32 or bf16 per flag) -> Xb bf16 [8192][1024]. 8 elems/thread.
// ---------------------------------------------------------------------------
__global__ __launch_bounds__(256) void xbf_kernel(const void* __restrict__ x,
                                                  u16* __restrict__ Xb,
                                                  const int* __restrict__ flagp) {
  const int f = *flagp;
  const size_t i = (size_t)blockIdx.x * 256 + threadIdx.x;
  if (f) {
    const float4* p = (const float4*)x;
    float4 a = p[i * 2], b = p[i * 2 + 1];
    u16 t[8] = {f2bf(a.x), f2bf(a.y), f2bf(a.z), f2bf(a.w),
                f2bf(b.x), f2bf(b.y), f2bf(b.z), f2bf(b.w)};
    *(uint4*)&Xb[i * 8] = *(const uint4*)t;
  } else {
    *(uint4*)&Xb[i * 8] = ((const uint4*)x)[i];
  }
}

// ---------------------------------------------------------------------------
// 8-wave deep-pipelined bf16 GEMM: C(MxN) = A(MxK=1024) @ Bt(NxK)^T + bias.
// Tile BM=128 x BN=256, BK=64. 512 thr = 8 waves (2M x 4N), 64x64 out/wave.
// Triple-buffered LDS; counted vmcnt(6) schedule (T3+T4); T2 XOR swizzle;
// T5 setprio. See round-1 notes.
// ---------------------------------------------------------------------------
__global__ __launch_bounds__(512, 2) void gemm8p_kernel(
    const u16* __restrict__ A,    // [M][1024] bf16
    const u16* __restrict__ Bt,   // [N][1024] bf16
    const u16* __restrict__ bias, // [N] bf16
    void* __restrict__ C, int ldc, int Mtiles,
    const int* __restrict__ flagp, int c_dyn)
{
  __shared__ __align__(16) u16 smem[73728];   // 147456 B
  u16* const As = smem;                       // 3 x [128*64]
  u16* const Bs = smem + 3 * 8192;            // 3 x [256*64]

  const bool cf32 = (c_dyn != 0) && (*flagp != 0);

  const int tid  = threadIdx.x;
  const int lane = tid & 63;
  const int w    = tid >> 6;
  const int quad = lane >> 4, l16 = lane & 15;
  const int wm   = w >> 2, wn = w & 3;

  // XCD-aware swizzle (nwg % 8 == 0 for both call sites: 704, 256)
  const int nwg = gridDim.x;
  const int wg  = (blockIdx.x & 7) * (nwg >> 3) + (blockIdx.x >> 3);
  const int mb  = wg % Mtiles, nb = wg / Mtiles;
  const int m0  = mb * 128, n0 = nb * 256;

  // staging geometry: j = tid + rd*512; rp = j>>3; slot s = j&7;
  // logical chunk = s ^ (rp&7)  (pre-swizzled global source, linear LDS dest)
  int ldsA[2]; size_t glA[2];
  int ldsB[2][2]; size_t glB[2][2];
#pragma unroll
  for (int rd = 0; rd < 2; rd++) {
    int j = tid + rd * 512, rp = j >> 3, s = j & 7;
    int cl = (s ^ (rp & 7)) * 8;
    ldsA[rd] = rp * 64 + s * 8;                       // rp in [0,128)
    glA[rd]  = (size_t)(m0 + rp) * 1024 + cl;
#pragma unroll
    for (int nh = 0; nh < 2; nh++) {
      int cc = (rp & 31) + nh * 32 + (rp >> 5) * 64;  // B(nh) region col
      ldsB[nh][rd] = cc * 64 + s * 8;
      glB[nh][rd]  = (size_t)(n0 + cc) * 1024 + cl;
    }
  }

#if HAVE_GLL
#define G8(g, l) gload_lds16((g), (l))
#else
#define G8(g, l) (*(uint4*)(l) = *(const uint4*)(g))
#endif
#define STG_A(t, bf)                                                       \
  if ((t) < NT_K) {                                                        \
    _Pragma("unroll") for (int rd = 0; rd < 2; rd++)                       \
      G8(A + glA[rd] + (t) * 64, As + (bf) * 8192 + ldsA[rd]);             \
  }
#define STG_B(nh, t, bf)                                                   \
  if ((t) < NT_K) {                                                        \
    _Pragma("unroll") for (int rd = 0; rd < 2; rd++)                       \
      G8(Bt + glB[nh][rd] + (t) * 64, Bs + (bf) * 16384 + ldsB[nh][rd]);   \
  }

  // frag-read offsets (swizzled chunk, lane-invariant XOR = l16&7)
  const int ck0  = ((quad)     ^ (l16 & 7)) * 8;
  const int ck1  = ((4 + quad) ^ (l16 & 7)) * 8;
  const int arow = (wm * 64 + l16) * 64;
  const int brow = (wn * 64 + l16) * 64;

  f32x4 acc[4][4];
#pragma unroll
  for (int i = 0; i < 4; i++)
#pragma unroll
    for (int j = 0; j < 4; j++) acc[i][j] = (f32x4){0.f, 0.f, 0.f, 0.f};

  short8 af[4][2], bA[2][2], bB[2][2];

#define READ_A(cur)                                                        \
  { const u16* pa = As + (cur) * 8192 + arow;                              \
    _Pragma("unroll") for (int m = 0; m < 4; m++) {                        \
      af[m][0] = *(const short8*)(pa + m * 1024 + ck0);                    \
      af[m][1] = *(const short8*)(pa + m * 1024 + ck1); } }
#define READ_B(dst, nh, cur)                                               \
  { const u16* pb = Bs + (cur) * 16384 + brow + (nh) * 2048;               \
    _Pragma("unroll") for (int n = 0; n < 2; n++) {                        \
      dst[n][0] = *(const short8*)(pb + n * 1024 + ck0);                   \
      dst[n][1] = *(const short8*)(pb + n * 1024 + ck1); } }
#define MM16(bfr, nh)                                                      \
  __builtin_amdgcn_s_setprio(1);                                           \
  _Pragma("unroll") for (int m = 0; m < 4; m++)                            \
    _Pragma("unroll") for (int n = 0; n < 2; n++) {                        \
      acc[m][(nh)*2+n] = __builtin_amdgcn_mfma_f32_16x16x32_bf16(          \
          af[m][0], bfr[n][0], acc[m][(nh)*2+n], 0, 0, 0);                 \
      acc[m][(nh)*2+n] = __builtin_amdgcn_mfma_f32_16x16x32_bf16(          \
          af[m][1], bfr[n][1], acc[m][(nh)*2+n], 0, 0, 0); }               \
  __builtin_amdgcn_s_setprio(0);
#define BARR { __builtin_amdgcn_s_barrier(); __builtin_amdgcn_sched_barrier(0); }

  // prologue: tiles 0 and 1 (12 loads); confirm tile 0, leave tile 1 in flight
  STG_A(0, 0); STG_B(1, 0, 0); STG_B(0, 0, 0);
  STG_A(1, 1); STG_B(1, 1, 1); STG_B(0, 1, 1);
  asm volatile("s_waitcnt vmcnt(6)");
  BARR;

#pragma unroll
  for (int kt = 0; kt < NT_K; kt++) {
    const int cur = kt % 3;
    const int stb = (kt + 2) % 3;
    // ---- phase 1: reads + A/B1 prefetch of tile kt+2, MFMA quadrant nh=0
    READ_A(cur); READ_B(bA, 0, cur);
    STG_A(kt + 2, stb); STG_B(1, kt + 2, stb);
    BARR;
    MM16(bA, 0);
    BARR;
    // ---- phase 2: B1 reads + B0 prefetch, MFMA quadrant nh=1
    READ_B(bB, 1, cur);
    STG_B(0, kt + 2, stb);
    BARR;
    MM16(bB, 1);
    if (kt < NT_K - 2)       { asm volatile("s_waitcnt vmcnt(6)"); }
    else if (kt == NT_K - 2) { asm volatile("s_waitcnt vmcnt(0)"); }
    BARR;
  }
#undef STG_A
#undef STG_B
#undef READ_A
#undef READ_B
#undef MM16
#undef BARR
#undef G8

  // ---- epilogue: acc -> per-wave LDS slice (XOR-swizzled) -> vector stores
  float bvv[4];
#pragma unroll
  for (int ni = 0; ni < 4; ni++)
    bvv[ni] = bf2f(bias[n0 + wn * 64 + ni * 16 + l16]);

  if (!cf32) {
    u16* cs = smem + w * 4096;          // 64x64 bf16 per wave
#pragma unroll
    for (int m = 0; m < 4; m++)
#pragma unroll
      for (int ni = 0; ni < 4; ni++)
#pragma unroll
        for (int r = 0; r < 4; r++) {
          int row = m * 16 + quad * 4 + r;
          int ch  = ((ni * 2 + (l16 >> 3)) ^ (row & 7)) * 8 + (l16 & 7);
          cs[row * 64 + ch] = f2bf(acc[m][ni][r] + bvv[ni]);
        }
    u16* Cb = (u16*)C;
#pragma unroll
    for (int i = 0; i < 8; i++) {
      int ch = lane + i * 64;
      int rr = ch >> 3, cc = ch & 7;
      short8 v = *(const short8*)(cs + rr * 64 + ((cc ^ (rr & 7)) * 8));
      *(short8*)&Cb[(size_t)(m0 + wm * 64 + rr) * ldc + n0 + wn * 64 + cc * 8] = v;
    }
  } else {
    float* cf = (float*)(void*)smem + w * 2048;   // 32x64 f32 per wave, 2 passes
#pragma unroll
    for (int pass = 0; pass < 2; pass++) {
#pragma unroll
      for (int m2 = 0; m2 < 2; m2++)
#pragma unroll
        for (int ni = 0; ni < 4; ni++)
#pragma unroll
          for (int r = 0; r < 4; r++) {
            int row = m2 * 16 + quad * 4 + r;
            int ch  = ((ni * 4 + (l16 >> 2)) ^ (row & 15)) * 4 + (l16 & 3);
            cf[row * 64 + ch] = acc[pass * 2 + m2][ni][r] + bvv[ni];
          }
      float* Cf = (float*)C;
#pragma unroll
      for (int i = 0; i < 8; i++) {
        int ch = lane + i * 64;
        int rr = ch >> 4, cc = ch & 15;
        f32x4 v = *(const f32x4*)(cf + rr * 64 + ((cc ^ (rr & 15)) * 4));
        *(f32x4*)&Cf[(size_t)(m0 + wm * 64 + pass * 32 + rr) * ldc +
                     n0 + wn * 64 + cc * 4] = v;
      }
    }
  }
}

// ---------------------------------------------------------------------------
// V transpose: Vt[(b*16+h)*64 + d][t] = P[b*T+t][vcol(h)+d]. 64x64 LDS tiles.
// ---------------------------------------------------------------------------
__global__ __launch_bounds__(256) void vt_kernel(const u16* __restrict__ P,
                                                 u16* __restrict__ Vt)
{
  const int tt = blockIdx.x * 64;
  const int bh = blockIdx.y;
  const int b = bh >> 4, h = bh & 15;
  const int vcol = 1552 + h * HEAD_DIM;
  __shared__ u16 t[64][65];
  const int tx = threadIdx.x & 63, ty = threadIdx.x >> 6;
#pragma unroll
  for (int rr = 0; rr < 16; rr++) {
    int r = ty * 16 + rr;
    t[r][tx] = P[((size_t)b * SEQ_T + tt + r) * PNS + vcol + tx];
  }
  __syncthreads();
#pragma unroll
  for (int rr = 0; rr < 16; rr++) {
    int d = ty * 16 + rr;
    Vt[((size_t)bh * 64 + d) * SEQ_T + tt + tx] = t[tx][d];
  }
}

// ---------------------------------------------------------------------------
// Causal flash attention, balanced-pair + K/V LDS double-buffer prefetch.
// CHANGED (round 2): LDS 50176 -> 40960 B so 4 blocks/CU co-reside (grid 1024
// = 4 x 256 CUs = ONE perfectly-packed round; was 3/CU -> 768+256 two-round
// tail, avg occupancy 20.6%). Achieved by replacing the per-chain Ps buffers
// with ONE per-wave Ps [16][64] used B-chain-then-A-chain (per-wave DS ops are
// in-order: PsA writes issued after paB reads cannot overtake them; no barrier
// needed). Stride-64 rows would be 16-way bank conflicted, so the 16B-chunk
// index is XOR-swizzled with row&7: reads spread 8 lanes x 8 chunk-groups over
// all 32 banks per cycle (throughput-optimal); writes <=2-way (free).
// V-frags re-read per chain (keeps VGPR ~70 <= 128 cap for 16 waves/CU).
// ---------------------------------------------------------------------------
__global__ __launch_bounds__(256, 4) void attn_kernel(
    const u16* __restrict__ P, const u16* __restrict__ Vt,
    u16* __restrict__ Y)
{
  const int bh  = blockIdx.x;
  const int b   = bh >> 4, h = bh & 15;
  const int p   = blockIdx.y;           // 0..15
  const int qtA = p, qtB = NTILES - 1 - p;
  const int tid = threadIdx.x;
  const int w   = tid >> 6;
  const int lane = tid & 63;
  const int quad = lane >> 4, l16 = lane & 15;
  const size_t rowb = (size_t)b * SEQ_T;
  const int qcol = 16 + h * PRIV;
  const int kcol = 784 + h * PRIV;

  __shared__ __align__(16) u16 Ks[2][64 * 64];   // [j][chunk^(j&7)]   16384 B
  __shared__ __align__(16) u16 Vs[2][64 * 64];   // [d][tchunk^(d&7)]  16384 B
  __shared__ __align__(16) u16 Ps[4][16 * 64];   // per-wave, single    8192 B
                                                 // [row][chunk^(row&7)] swz

  const float csc = 0.18033688011112042f;  // (1/8)*log2(e)
  const int d0  = quad * 8;
  const int cq0 = (d0 < 16) ? d0 : (qcol + d0 - 16);
  const int iA = qtA * 64 + w * 16, iB = qtB * 64 + w * 16;
  const u16* qrowA = P + (rowb + iA + l16) * PNS;
  const u16* qrowB = P + (rowb + iB + l16) * PNS;
  short8 qaA0 = *(const short8*)&qrowA[cq0];
  short8 qaA1 = *(const short8*)&qrowA[qcol + 16 + d0];
  short8 qaB0 = *(const short8*)&qrowB[cq0];
  short8 qaB1 = *(const short8*)&qrowB[qcol + 16 + d0];
#pragma unroll
  for (int e = 0; e < 8; e++) {
    qaA0[e] = (short)f2bf(bf2f((u16)qaA0[e]) * csc);
    qaA1[e] = (short)f2bf(bf2f((u16)qaA1[e]) * csc);
    qaB0[e] = (short)f2bf(bf2f((u16)qaB0[e]) * csc);
    qaB1[e] = (short)f2bf(bf2f((u16)qaB1[e]) * csc);
  }
  short8 ones;
#pragma unroll
  for (int e = 0; e < 8; e++) ones[e] = (short)0x3F80;

#if HAVE_GLL
#define GLOADA(g, l) gload_lds16((g), (l))
#else
#define GLOADA(g, l) (*(uint4*)(l) = *(const uint4*)(g))
#endif
#define STAGE_KV(k0, bb)                                                       \
  {                                                                            \
    _Pragma("unroll") for (int i2 = 0; i2 < 2; i2++) {                         \
      int c   = tid + i2 * 256;                                                \
      int row = c >> 3;                                                        \
      int dg  = ((c & 7) ^ (row & 7)) * 8;                                     \
      int col = (dg < 16) ? dg : (kcol + dg - 16);                             \
      GLOADA(&P[(rowb + (k0) + row) * PNS + col], &Ks[bb][c * 8]);             \
      GLOADA(&Vt[((size_t)bh * 64 + row) * SEQ_T + (k0) + dg], &Vs[bb][c * 8]);\
    }                                                                          \
  }

  f32x4 accyA[4], accyB[4], acclA, acclB;
#pragma unroll
  for (int g = 0; g < 4; g++) {
    accyA[g] = (f32x4){0.f, 0.f, 0.f, 0.f};
    accyB[g] = (f32x4){0.f, 0.f, 0.f, 0.f};
  }
  acclA = (f32x4){0.f, 0.f, 0.f, 0.f};
  acclB = (f32x4){0.f, 0.f, 0.f, 0.f};

  const int nkt = qtB + 1;
  STAGE_KV(0, 0);
  __syncthreads();

  for (int kt = 0; kt < nkt; kt++) {
    const int cur = kt & 1;
    const int k0  = kt * 64;
    if (kt + 1 < nkt) STAGE_KV((kt + 1) * 64, 1 - cur);  // prefetch, no wait

    const bool doA = (kt <= qtA);

    // ---- S = Qs K^T for both chains (K frags from LDS, shared) ----
    float svA[4][4], svB[4][4];
#pragma unroll
    for (int g = 0; g < 4; g++) {
      int j = g * 16 + l16;
      short8 kb0 = *(const short8*)&Ks[cur][j * 64 + ((quad    ) ^ (j & 7)) * 8];
      short8 kb1 = *(const short8*)&Ks[cur][j * 64 + ((quad + 4) ^ (j & 7)) * 8];
      f32x4 sB = (f32x4){0.f, 0.f, 0.f, 0.f};
      sB = __builtin_amdgcn_mfma_f32_16x16x32_bf16(qaB0, kb0, sB, 0, 0, 0);
      sB = __builtin_amdgcn_mfma_f32_16x16x32_bf16(qaB1, kb1, sB, 0, 0, 0);
#pragma unroll
      for (int r = 0; r < 4; r++) svB[g][r] = sB[r];
      if (doA) {
        f32x4 sA = (f32x4){0.f, 0.f, 0.f, 0.f};
        sA = __builtin_amdgcn_mfma_f32_16x16x32_bf16(qaA0, kb0, sA, 0, 0, 0);
        sA = __builtin_amdgcn_mfma_f32_16x16x32_bf16(qaA1, kb1, sA, 0, 0, 0);
#pragma unroll
        for (int r = 0; r < 4; r++) svA[g][r] = sA[r];
      }
    }
    if (kt == qtA && doA) {
#pragma unroll
      for (int g = 0; g < 4; g++)
#pragma unroll
        for (int r = 0; r < 4; r++) {
          int gi = iA + quad * 4 + r;
          int gj = k0 + g * 16 + l16;
          if (gj > gi) svA[g][r] = -__builtin_inff();
        }
    }
    if (kt == qtB) {
#pragma unroll
      for (int g = 0; g < 4; g++)
#pragma unroll
        for (int r = 0; r < 4; r++) {
          int gi = iB + quad * 4 + r;
          int gj = k0 + g * 16 + l16;
          if (gj > gi) svB[g][r] = -__builtin_inff();
        }
    }

    // ---- chain B: p=exp2(s) -> Ps (swizzled) -> PV ----
#pragma unroll
    for (int g = 0; g < 4; g++)
#pragma unroll
      for (int r = 0; r < 4; r++) {
        int row = quad * 4 + r;
        Ps[w][row * 64 + ((g * 2 + (l16 >> 3)) ^ (row & 7)) * 8 + (l16 & 7)] =
            truncbf(EXP2(svB[g][r]));
      }
#pragma unroll
    for (int kf = 0; kf < 2; kf++) {
      short8 vb[4];
#pragma unroll
      for (int g2 = 0; g2 < 4; g2++) {
        int rv = g2 * 16 + l16;
        vb[g2] = *(const short8*)&Vs[cur][rv * 64 + (((kf * 4 + quad) ^ (rv & 7)) * 8)];
      }
      short8 paB = *(const short8*)&Ps[w][l16 * 64 + (((kf * 4 + quad) ^ (l16 & 7)) * 8)];
      acclB = __builtin_amdgcn_mfma_f32_16x16x32_bf16(paB, ones, acclB, 0, 0, 0);
#pragma unroll
      for (int g2 = 0; g2 < 4; g2++)
        accyB[g2] = __builtin_amdgcn_mfma_f32_16x16x32_bf16(paB, vb[g2], accyB[g2], 0, 0, 0);
    }

    // ---- chain A: reuses the SAME per-wave Ps buffer (DS in-order: these
    // writes were issued after the paB reads above and cannot overtake) ----
    if (doA) {
#pragma unroll
      for (int g = 0; g < 4; g++)
#pragma unroll
        for (int r = 0; r < 4; r++) {
          int row = quad * 4 + r;
          Ps[w][row * 64 + ((g * 2 + (l16 >> 3)) ^ (row & 7)) * 8 + (l16 & 7)] =
              truncbf(EXP2(svA[g][r]));
        }
#pragma unroll
      for (int kf = 0; kf < 2; kf++) {
        short8 vb[4];
#pragma unroll
        for (int g2 = 0; g2 < 4; g2++) {
          int rv = g2 * 16 + l16;
          vb[g2] = *(const short8*)&Vs[cur][rv * 64 + (((kf * 4 + quad) ^ (rv & 7)) * 8)];
        }
        short8 paA = *(const short8*)&Ps[w][l16 * 64 + (((kf * 4 + quad) ^ (l16 & 7)) * 8)];
        acclA = __builtin_amdgcn_mfma_f32_16x16x32_bf16(paA, ones, acclA, 0, 0, 0);
#pragma unroll
        for (int g2 = 0; g2 < 4; g2++)
          accyA[g2] = __builtin_amdgcn_mfma_f32_16x16x32_bf16(paA, vb[g2], accyA[g2], 0, 0, 0);
      }
    }

    if (kt + 1 < nkt) __syncthreads();  // drains overlapped prefetch
  }
#undef STAGE_KV
#undef GLOADA

  float invA[4], invB[4];
#pragma unroll
  for (int r = 0; r < 4; r++) {
    invA[r] = 1.0f / acclA[r];
    invB[r] = 1.0f / acclB[r];
  }
#pragma unroll
  for (int g2 = 0; g2 < 4; g2++) {
    int col = h * HEAD_DIM + g2 * 16 + l16;
#pragma unroll
    for (int r = 0; r < 4; r++) {
      int giA = iA + quad * 4 + r;
      int giB = iB + quad * 4 + r;
      Y[(rowb + giA) * N_EMBD + col] = f2bf(accyA[g2][r] * invA[r]);
      Y[(rowb + giB) * N_EMBD + col] = f2bf(accyB[g2][r] * invB[r]);
    }
  }
}

// ---------------------------------------------------------------------------
extern "C" void kernel_launch(void* const* d_in, const int* in_sizes, int n_in,
                              void* d_out, int out_size, void* d_ws, size_t ws_size,
                              hipStream_t stream) {
  (void)in_sizes; (void)n_in; (void)out_size; (void)ws_size;
  const void* x   = d_in[0];
  const void* Wsh = d_in[1];
  const void* bsh = d_in[2];
  const void* Wq  = d_in[3];
  const void* bq  = d_in[4];
  const void* Wk  = d_in[5];
  const void* bk  = d_in[6];
  const void* Wv  = d_in[7];
  const void* bv  = d_in[8];
  const void* Wo  = d_in[9];
  const void* bo  = d_in[10];

  char* wsb = (char*)d_ws;
  int* flag = (int*)wsb;
  u16* ws16 = (u16*)(wsb + 64);
  u16* Wcat = ws16;                                   // PNS*1024 (transposed)
  u16* bcat = Wcat + (size_t)PNS * N_EMBD;            // PNS
  u16* Woc  = bcat + PNS;                             // 1024*1024 (transposed)
  u16* boc  = Woc + (size_t)N_EMBD * N_EMBD;          // 1024
  u16* Pb   = boc + N_EMBD;                           // 8192*2816
  u16* Yb   = Pb + (size_t)M_ROWS * PNS;              // 8192*1024 (also Xb)
  u16* Vtb  = Yb + (size_t)M_ROWS * N_EMBD;           // 64*64*2048
  u16* Xb   = Yb;   // x->bf16 staging aliases Yb: proj reads Xb, attn writes Yb later

  detect_kernel<<<dim3(1), dim3(256), 0, stream>>>((const u16*)x, flag);
  pack_t_kernel<<<dim3(16, 16, 6), dim3(256), 0, stream>>>(
      Wsh, Wq, Wk, Wv, Wo, bsh, bq, bk, bv, bo, Wcat, Woc, bcat, boc, flag);
  xbf_kernel<<<dim3(M_ROWS * N_EMBD / (256 * 8)), dim3(256), 0, stream>>>(
      x, Xb, flag);
  // proj GEMM: [8192 x 2816] = Xb @ Wcat^T, bf16 out
  gemm8p_kernel<<<dim3(64 * (PNS / 256)), dim3(512), 0, stream>>>(
      Xb, Wcat, bcat, Pb, PNS, 64, flag, 0);
  vt_kernel<<<dim3(SEQ_T / 64, BATCH * N_HEADS), dim3(256), 0, stream>>>(
      Pb, Vtb);
  attn_kernel<<<dim3(BATCH * N_HEADS, NTILES / 2), dim3(256), 0, stream>>>(
      Pb, Vtb, Yb);
  // out GEMM: [8192 x 1024] = Yb @ Woc^T, f32 out when inputs were f32
  gemm8p_kernel<<<dim3(64 * (N_EMBD / 256)), dim3(512), 0, stream>>>(
      Yb, Woc, boc, d_out, N_EMBD, 64, flag, 1);
}

// Round 4
// 283.977 us; speedup vs baseline: 1.2161x; 1.2161x over previous
//
#include <hip/hip_runtime.h>
#include <hip/hip_bf16.h>

typedef unsigned short u16;
typedef short short8 __attribute__((ext_vector_type(8)));
typedef float f32x4 __attribute__((ext_vector_type(4)));

#define N_EMBD   1024
#define N_HEADS  16
#define HEAD_DIM 64
#define PRIV     48
#define SEQ_T    2048
#define BATCH    4
#define M_ROWS   (BATCH*SEQ_T)   // 8192
#define PNS      2816            // [share 16 | q 768 | k 768 | v 1024] = 2576 -> 11*256
#define NTILES   (SEQ_T/64)      // 32
#define NT_K     16              // K=1024 / BK=64

#if __has_builtin(__builtin_amdgcn_exp2f)
#define EXP2(x) __builtin_amdgcn_exp2f(x)
#else
#define EXP2(x) exp2f(x)
#endif

#if __has_builtin(__builtin_amdgcn_global_load_lds)
#define HAVE_GLL 1
#else
#define HAVE_GLL 0
#endif

__device__ __forceinline__ u16 f2bf(float f) {
  __hip_bfloat16 h = __float2bfloat16(f);
  return *reinterpret_cast<u16*>(&h);
}
__device__ __forceinline__ float bf2f(u16 s) {
  __hip_bfloat16 h;
  *reinterpret_cast<u16*>(&h) = s;
  return __bfloat162float(h);
}
__device__ __forceinline__ float loadv(const void* p, size_t i, int isf32) {
  return isf32 ? ((const float*)p)[i] : bf2f(((const u16*)p)[i]);
}
__device__ __forceinline__ u16 truncbf(float f) {
  unsigned u = __builtin_bit_cast(unsigned, f);
  return (u16)(u >> 16);
}
#if HAVE_GLL
__device__ __forceinline__ void gload_lds16(const u16* g, u16* l) {
  __builtin_amdgcn_global_load_lds(
      (const __attribute__((address_space(1))) void*)g,
      (__attribute__((address_space(3))) void*)l, 16, 0, 0);
}
#endif

// ---------------------------------------------------------------------------
// Dtype detector (1 = f32 inputs).
// ---------------------------------------------------------------------------
__global__ __launch_bounds__(256) void detect_kernel(const u16* __restrict__ x,
                                                     int* __restrict__ flag) {
  __shared__ int cnt;
  if (threadIdx.x == 0) cnt = 0;
  __syncthreads();
  u16 v = x[2 * threadIdx.x];
  int e = (v >> 7) & 0xFF;
  int junk = (e >= 0xC0 || (e != 0 && e <= 0x30)) ? 1 : 0;
  if (junk) atomicAdd(&cnt, 1);
  __syncthreads();
  if (threadIdx.x == 0) *flag = (cnt > 16) ? 1 : 0;
}

// ---------------------------------------------------------------------------
// Transposing pack (weights -> [n][k] bf16) + z=5 slice does zero-pad + biases.
// ---------------------------------------------------------------------------
__global__ __launch_bounds__(256) void pack_t_kernel(
    const void* __restrict__ Wsh, const void* __restrict__ Wq,
    const void* __restrict__ Wk,  const void* __restrict__ Wv,
    const void* __restrict__ Wo,
    const void* __restrict__ bsh, const void* __restrict__ bq,
    const void* __restrict__ bk,  const void* __restrict__ bv,
    const void* __restrict__ bo,
    u16* __restrict__ Wcat, u16* __restrict__ Woc,
    u16* __restrict__ bcat, u16* __restrict__ boc,
    const int* __restrict__ flagp)
{
  const int f = *flagp;
  if (blockIdx.z == 5) {  // pad + biases
    const int flat = blockIdx.y * 16 + blockIdx.x;
    const int padN = (PNS - 2576) * 1024;
    for (int i = flat * 256 + threadIdx.x; i < padN; i += 256 * 256)
      Wcat[(size_t)2576 * 1024 + i] = 0;
    if (flat == 0) {
      for (int c = threadIdx.x; c < PNS; c += 256) {
        float v = 0.f;
        if (c < 16)        v = loadv(bsh, c, f);
        else if (c < 784)  v = loadv(bq, c - 16, f);
        else if (c < 1552) v = loadv(bk, c - 784, f);
        else if (c < 2576) v = loadv(bv, c - 1552, f);
        bcat[c] = f2bf(v);
      }
    } else if (flat == 1) {
      for (int c = threadIdx.x; c < N_EMBD; c += 256)
        boc[c] = f2bf(loadv(bo, c, f));
    }
    return;
  }
  const void* src; u16* dst; int N, rowOff;
  switch (blockIdx.z) {
    case 0: src = Wsh; dst = Wcat; N = 16;   rowOff = 0;    break;
    case 1: src = Wq;  dst = Wcat; N = 768;  rowOff = 16;   break;
    case 2: src = Wk;  dst = Wcat; N = 768;  rowOff = 784;  break;
    case 3: src = Wv;  dst = Wcat; N = 1024; rowOff = 1552; break;
    default:src = Wo;  dst = Woc;  N = 1024; rowOff = 0;    break;
  }
  const int n0 = blockIdx.x * 64;
  if (n0 >= N) return;
  const int k0 = blockIdx.y * 64;
  __shared__ u16 t[64][65];
  const int tx = threadIdx.x & 63, ty = threadIdx.x >> 6;
#pragma unroll
  for (int rr = 0; rr < 16; rr++) {
    int k = k0 + ty * 16 + rr;
    int n = n0 + tx;
    float v = (n < N) ? loadv(src, (size_t)k * N + n, f) : 0.f;
    t[ty * 16 + rr][tx] = f2bf(v);
  }
  __syncthreads();
#pragma unroll
  for (int rr = 0; rr < 16; rr++) {
    int n = ty * 16 + rr;
    if (n0 + n < N)
      dst[(size_t)(rowOff + n0 + n) * 1024 + k0 + tx] = t[tx][n];
  }
}

// ---------------------------------------------------------------------------
// x (f32 or bf16 per flag) -> Xb bf16 [8192][1024]. 8 elems/thread.
// ---------------------------------------------------------------------------
__global__ __launch_bounds__(256) void xbf_kernel(const void* __restrict__ x,
                                                  u16* __restrict__ Xb,
                                                  const int* __restrict__ flagp) {
  const int f = *flagp;
  const size_t i = (size_t)blockIdx.x * 256 + threadIdx.x;
  if (f) {
    const float4* p = (const float4*)x;
    float4 a = p[i * 2], b = p[i * 2 + 1];
    u16 t[8] = {f2bf(a.x), f2bf(a.y), f2bf(a.z), f2bf(a.w),
                f2bf(b.x), f2bf(b.y), f2bf(b.z), f2bf(b.w)};
    *(uint4*)&Xb[i * 8] = *(const uint4*)t;
  } else {
    *(uint4*)&Xb[i * 8] = ((const uint4*)x)[i];
  }
}

// ---------------------------------------------------------------------------
// 8-wave deep-pipelined bf16 GEMM: C(MxN) = A(MxK=1024) @ Bt(NxK)^T + bias.
// Tile BM=128 x BN=256, BK=64. 512 thr = 8 waves (2M x 4N), 64x64 out/wave.
// Triple-buffered LDS; counted vmcnt(6) schedule (T3+T4); T2 XOR swizzle;
// T5 setprio. See round-1 notes.
// ---------------------------------------------------------------------------
__global__ __launch_bounds__(512, 2) void gemm8p_kernel(
    const u16* __restrict__ A,    // [M][1024] bf16
    const u16* __restrict__ Bt,   // [N][1024] bf16
    const u16* __restrict__ bias, // [N] bf16
    void* __restrict__ C, int ldc, int Mtiles,
    const int* __restrict__ flagp, int c_dyn)
{
  __shared__ __align__(16) u16 smem[73728];   // 147456 B
  u16* const As = smem;                       // 3 x [128*64]
  u16* const Bs = smem + 3 * 8192;            // 3 x [256*64]

  const bool cf32 = (c_dyn != 0) && (*flagp != 0);

  const int tid  = threadIdx.x;
  const int lane = tid & 63;
  const int w    = tid >> 6;
  const int quad = lane >> 4, l16 = lane & 15;
  const int wm   = w >> 2, wn = w & 3;

  // XCD-aware swizzle (nwg % 8 == 0 for both call sites: 704, 256)
  const int nwg = gridDim.x;
  const int wg  = (blockIdx.x & 7) * (nwg >> 3) + (blockIdx.x >> 3);
  const int mb  = wg % Mtiles, nb = wg / Mtiles;
  const int m0  = mb * 128, n0 = nb * 256;

  // staging geometry: j = tid + rd*512; rp = j>>3; slot s = j&7;
  // logical chunk = s ^ (rp&7)  (pre-swizzled global source, linear LDS dest)
  int ldsA[2]; size_t glA[2];
  int ldsB[2][2]; size_t glB[2][2];
#pragma unroll
  for (int rd = 0; rd < 2; rd++) {
    int j = tid + rd * 512, rp = j >> 3, s = j & 7;
    int cl = (s ^ (rp & 7)) * 8;
    ldsA[rd] = rp * 64 + s * 8;                       // rp in [0,128)
    glA[rd]  = (size_t)(m0 + rp) * 1024 + cl;
#pragma unroll
    for (int nh = 0; nh < 2; nh++) {
      int cc = (rp & 31) + nh * 32 + (rp >> 5) * 64;  // B(nh) region col
      ldsB[nh][rd] = cc * 64 + s * 8;
      glB[nh][rd]  = (size_t)(n0 + cc) * 1024 + cl;
    }
  }

#if HAVE_GLL
#define G8(g, l) gload_lds16((g), (l))
#else
#define G8(g, l) (*(uint4*)(l) = *(const uint4*)(g))
#endif
#define STG_A(t, bf)                                                       \
  if ((t) < NT_K) {                                                        \
    _Pragma("unroll") for (int rd = 0; rd < 2; rd++)                       \
      G8(A + glA[rd] + (t) * 64, As + (bf) * 8192 + ldsA[rd]);             \
  }
#define STG_B(nh, t, bf)                                                   \
  if ((t) < NT_K) {                                                        \
    _Pragma("unroll") for (int rd = 0; rd < 2; rd++)                       \
      G8(Bt + glB[nh][rd] + (t) * 64, Bs + (bf) * 16384 + ldsB[nh][rd]);   \
  }

  // frag-read offsets (swizzled chunk, lane-invariant XOR = l16&7)
  const int ck0  = ((quad)     ^ (l16 & 7)) * 8;
  const int ck1  = ((4 + quad) ^ (l16 & 7)) * 8;
  const int arow = (wm * 64 + l16) * 64;
  const int brow = (wn * 64 + l16) * 64;

  f32x4 acc[4][4];
#pragma unroll
  for (int i = 0; i < 4; i++)
#pragma unroll
    for (int j = 0; j < 4; j++) acc[i][j] = (f32x4){0.f, 0.f, 0.f, 0.f};

  short8 af[4][2], bA[2][2], bB[2][2];

#define READ_A(cur)                                                        \
  { const u16* pa = As + (cur) * 8192 + arow;                              \
    _Pragma("unroll") for (int m = 0; m < 4; m++) {                        \
      af[m][0] = *(const short8*)(pa + m * 1024 + ck0);                    \
      af[m][1] = *(const short8*)(pa + m * 1024 + ck1); } }
#define READ_B(dst, nh, cur)                                               \
  { const u16* pb = Bs + (cur) * 16384 + brow + (nh) * 2048;               \
    _Pragma("unroll") for (int n = 0; n < 2; n++) {                        \
      dst[n][0] = *(const short8*)(pb + n * 1024 + ck0);                   \
      dst[n][1] = *(const short8*)(pb + n * 1024 + ck1); } }
#define MM16(bfr, nh)                                                      \
  __builtin_amdgcn_s_setprio(1);                                           \
  _Pragma("unroll") for (int m = 0; m < 4; m++)                            \
    _Pragma("unroll") for (int n = 0; n < 2; n++) {                        \
      acc[m][(nh)*2+n] = __builtin_amdgcn_mfma_f32_16x16x32_bf16(          \
          af[m][0], bfr[n][0], acc[m][(nh)*2+n], 0, 0, 0);                 \
      acc[m][(nh)*2+n] = __builtin_amdgcn_mfma_f32_16x16x32_bf16(          \
          af[m][1], bfr[n][1], acc[m][(nh)*2+n], 0, 0, 0); }               \
  __builtin_amdgcn_s_setprio(0);
#define BARR { __builtin_amdgcn_s_barrier(); __builtin_amdgcn_sched_barrier(0); }

  // prologue: tiles 0 and 1 (12 loads); confirm tile 0, leave tile 1 in flight
  STG_A(0, 0); STG_B(1, 0, 0); STG_B(0, 0, 0);
  STG_A(1, 1); STG_B(1, 1, 1); STG_B(0, 1, 1);
  asm volatile("s_waitcnt vmcnt(6)");
  BARR;

#pragma unroll
  for (int kt = 0; kt < NT_K; kt++) {
    const int cur = kt % 3;
    const int stb = (kt + 2) % 3;
    // ---- phase 1: reads + A/B1 prefetch of tile kt+2, MFMA quadrant nh=0
    READ_A(cur); READ_B(bA, 0, cur);
    STG_A(kt + 2, stb); STG_B(1, kt + 2, stb);
    BARR;
    MM16(bA, 0);
    BARR;
    // ---- phase 2: B1 reads + B0 prefetch, MFMA quadrant nh=1
    READ_B(bB, 1, cur);
    STG_B(0, kt + 2, stb);
    BARR;
    MM16(bB, 1);
    if (kt < NT_K - 2)       { asm volatile("s_waitcnt vmcnt(6)"); }
    else if (kt == NT_K - 2) { asm volatile("s_waitcnt vmcnt(0)"); }
    BARR;
  }
#undef STG_A
#undef STG_B
#undef READ_A
#undef READ_B
#undef MM16
#undef BARR
#undef G8

  // ---- epilogue: acc -> per-wave LDS slice (XOR-swizzled) -> vector stores
  float bvv[4];
#pragma unroll
  for (int ni = 0; ni < 4; ni++)
    bvv[ni] = bf2f(bias[n0 + wn * 64 + ni * 16 + l16]);

  if (!cf32) {
    u16* cs = smem + w * 4096;          // 64x64 bf16 per wave
#pragma unroll
    for (int m = 0; m < 4; m++)
#pragma unroll
      for (int ni = 0; ni < 4; ni++)
#pragma unroll
        for (int r = 0; r < 4; r++) {
          int row = m * 16 + quad * 4 + r;
          int ch  = ((ni * 2 + (l16 >> 3)) ^ (row & 7)) * 8 + (l16 & 7);
          cs[row * 64 + ch] = f2bf(acc[m][ni][r] + bvv[ni]);
        }
    u16* Cb = (u16*)C;
#pragma unroll
    for (int i = 0; i < 8; i++) {
      int ch = lane + i * 64;
      int rr = ch >> 3, cc = ch & 7;
      short8 v = *(const short8*)(cs + rr * 64 + ((cc ^ (rr & 7)) * 8));
      *(short8*)&Cb[(size_t)(m0 + wm * 64 + rr) * ldc + n0 + wn * 64 + cc * 8] = v;
    }
  } else {
    float* cf = (float*)(void*)smem + w * 2048;   // 32x64 f32 per wave, 2 passes
#pragma unroll
    for (int pass = 0; pass < 2; pass++) {
#pragma unroll
      for (int m2 = 0; m2 < 2; m2++)
#pragma unroll
        for (int ni = 0; ni < 4; ni++)
#pragma unroll
          for (int r = 0; r < 4; r++) {
            int row = m2 * 16 + quad * 4 + r;
            int ch  = ((ni * 4 + (l16 >> 2)) ^ (row & 15)) * 4 + (l16 & 3);
            cf[row * 64 + ch] = acc[pass * 2 + m2][ni][r] + bvv[ni];
          }
      float* Cf = (float*)C;
#pragma unroll
      for (int i = 0; i < 8; i++) {
        int ch = lane + i * 64;
        int rr = ch >> 4, cc = ch & 15;
        f32x4 v = *(const f32x4*)(cf + rr * 64 + ((cc ^ (rr & 15)) * 4));
        *(f32x4*)&Cf[(size_t)(m0 + wm * 64 + pass * 32 + rr) * ldc +
                     n0 + wn * 64 + cc * 4] = v;
      }
    }
  }
}

// ---------------------------------------------------------------------------
// V transpose: Vt[(b*16+h)*64 + d][t] = P[b*T+t][vcol(h)+d]. 64x64 LDS tiles.
// ---------------------------------------------------------------------------
__global__ __launch_bounds__(256) void vt_kernel(const u16* __restrict__ P,
                                                 u16* __restrict__ Vt)
{
  const int tt = blockIdx.x * 64;
  const int bh = blockIdx.y;
  const int b = bh >> 4, h = bh & 15;
  const int vcol = 1552 + h * HEAD_DIM;
  __shared__ u16 t[64][65];
  const int tx = threadIdx.x & 63, ty = threadIdx.x >> 6;
#pragma unroll
  for (int rr = 0; rr < 16; rr++) {
    int r = ty * 16 + rr;
    t[r][tx] = P[((size_t)b * SEQ_T + tt + r) * PNS + vcol + tx];
  }
  __syncthreads();
#pragma unroll
  for (int rr = 0; rr < 16; rr++) {
    int d = ty * 16 + rr;
    Vt[((size_t)bh * 64 + d) * SEQ_T + tt + tx] = t[tx][d];
  }
}

// ---------------------------------------------------------------------------
// Causal flash attention, balanced-pair. (Round-4 resubmit of round-3 source:
// audited for hang/fault -- barrier uniformity, vmcnt ledger, buffer rotation,
// OOB, endpgm drain all verified; round-3 bench died to container infra.)
// K/V TRIPLE-buffered with counted vmcnt (T3+T4): per tile issue stage(kt+2),
// bottom wait vmcnt(4) -- 4 loads (next-next tile) stay in flight across the
// barrier instead of draining to 0 (round-1's ~4500cy/tile stall was the
// vmcnt(0) drain of a 1-deep prefetch). Ledger (4 loads/thread/tile):
//   prologue: S0,S1 issued (8) -> vmcnt(4) confirms S0.
//   iter kt<=nkt-3: issue S(kt+2) (out=8); bottom vmcnt(4) confirms S(kt+1).
//   iter nkt-2: no issue (out=4); bottom vmcnt(0) confirms S(nkt-1).
//   iter nkt-1: no issue, no bottom wait. No DMA outstanding at endpgm.
// Buffer rotation: S(kt+2) writes buf (kt+2)%3 = (kt-1)%3, whose readers all
// passed the bottom barrier of iter kt-1 before any wave enters iter kt.
// LDS = 3*8K(K) + 3*8K(V) + 17K(Ps) = 66560 B -> 2 blocks/CU; grid 1024 =
// 2 x 512: perfectly packed two rounds, zero tail; resident blocks 512 < 768
// keeps the cache regime of round-1. T5 setprio around MFMA clusters.
// ---------------------------------------------------------------------------
__global__ __launch_bounds__(256, 2) void attn_kernel(
    const u16* __restrict__ P, const u16* __restrict__ Vt,
    u16* __restrict__ Y)
{
  const int bh  = blockIdx.x;
  const int b   = bh >> 4, h = bh & 15;
  const int p   = blockIdx.y;           // 0..15
  const int qtA = p, qtB = NTILES - 1 - p;
  const int tid = threadIdx.x;
  const int w   = tid >> 6;
  const int lane = tid & 63;
  const int quad = lane >> 4, l16 = lane & 15;
  const size_t rowb = (size_t)b * SEQ_T;
  const int qcol = 16 + h * PRIV;
  const int kcol = 784 + h * PRIV;

  __shared__ __align__(16) u16 Ks[3][64 * 64];     // [j][chunk^(j&7)]
  __shared__ __align__(16) u16 Vs[3][64 * 64];     // [d][tchunk^(d&7)]
  __shared__ __align__(16) u16 Ps[4][2][16 * 68];  // [wave][chain]

  const float csc = 0.18033688011112042f;  // (1/8)*log2(e)
  const int d0  = quad * 8;
  const int cq0 = (d0 < 16) ? d0 : (qcol + d0 - 16);
  const int iA = qtA * 64 + w * 16, iB = qtB * 64 + w * 16;
  const u16* qrowA = P + (rowb + iA + l16) * PNS;
  const u16* qrowB = P + (rowb + iB + l16) * PNS;
  short8 qaA0 = *(const short8*)&qrowA[cq0];
  short8 qaA1 = *(const short8*)&qrowA[qcol + 16 + d0];
  short8 qaB0 = *(const short8*)&qrowB[cq0];
  short8 qaB1 = *(const short8*)&qrowB[qcol + 16 + d0];
#pragma unroll
  for (int e = 0; e < 8; e++) {
    qaA0[e] = (short)f2bf(bf2f((u16)qaA0[e]) * csc);
    qaA1[e] = (short)f2bf(bf2f((u16)qaA1[e]) * csc);
    qaB0[e] = (short)f2bf(bf2f((u16)qaB0[e]) * csc);
    qaB1[e] = (short)f2bf(bf2f((u16)qaB1[e]) * csc);
  }
  short8 ones;
#pragma unroll
  for (int e = 0; e < 8; e++) ones[e] = (short)0x3F80;

  const int nkt = qtB + 1;   // >= 17 always

#if HAVE_GLL
#define GLOADA(g, l) gload_lds16((g), (l))
#else
#define GLOADA(g, l) (*(uint4*)(l) = *(const uint4*)(g))
#endif
  // staging: c = tid + i2*256; row = c>>3; phys chunk = c&7; logical = pc^(row&7)
#define STAGE_KV(t, bb)                                                        \
  {                                                                            \
    const int kk0 = (t) * 64;                                                  \
    _Pragma("unroll") for (int i2 = 0; i2 < 2; i2++) {                         \
      int c   = tid + i2 * 256;                                                \
      int row = c >> 3;                                                        \
      int dg  = ((c & 7) ^ (row & 7)) * 8;                                     \
      int col = (dg < 16) ? dg : (kcol + dg - 16);                             \
      GLOADA(&P[(rowb + kk0 + row) * PNS + col], &Ks[bb][c * 8]);              \
      GLOADA(&Vt[((size_t)bh * 64 + row) * SEQ_T + kk0 + dg], &Vs[bb][c * 8]); \
    }                                                                          \
  }

  f32x4 accyA[4], accyB[4], acclA, acclB;
#pragma unroll
  for (int g = 0; g < 4; g++) {
    accyA[g] = (f32x4){0.f, 0.f, 0.f, 0.f};
    accyB[g] = (f32x4){0.f, 0.f, 0.f, 0.f};
  }
  acclA = (f32x4){0.f, 0.f, 0.f, 0.f};
  acclB = (f32x4){0.f, 0.f, 0.f, 0.f};

  // prologue: tiles 0,1 in flight; confirm 0, leave 1 outstanding
  STAGE_KV(0, 0);
  STAGE_KV(1, 1);
  asm volatile("s_waitcnt vmcnt(4)" ::: "memory");
  __builtin_amdgcn_sched_barrier(0);
  __builtin_amdgcn_s_barrier();

  for (int kt = 0; kt < nkt; kt++) {
    const int cur = kt % 3;
    const int k0  = kt * 64;
    if (kt + 2 < nkt) STAGE_KV(kt + 2, (kt + 2) % 3);   // 2-deep prefetch

    const bool doA = (kt <= qtA);

    // ---- S = Qs K^T for both chains (K frags from LDS, shared) ----
    float svA[4][4], svB[4][4];
    __builtin_amdgcn_s_setprio(1);
#pragma unroll
    for (int g = 0; g < 4; g++) {
      int j = g * 16 + l16;
      short8 kb0 = *(const short8*)&Ks[cur][j * 64 + ((quad    ) ^ (j & 7)) * 8];
      short8 kb1 = *(const short8*)&Ks[cur][j * 64 + ((quad + 4) ^ (j & 7)) * 8];
      f32x4 sB = (f32x4){0.f, 0.f, 0.f, 0.f};
      sB = __builtin_amdgcn_mfma_f32_16x16x32_bf16(qaB0, kb0, sB, 0, 0, 0);
      sB = __builtin_amdgcn_mfma_f32_16x16x32_bf16(qaB1, kb1, sB, 0, 0, 0);
#pragma unroll
      for (int r = 0; r < 4; r++) svB[g][r] = sB[r];
      if (doA) {
        f32x4 sA = (f32x4){0.f, 0.f, 0.f, 0.f};
        sA = __builtin_amdgcn_mfma_f32_16x16x32_bf16(qaA0, kb0, sA, 0, 0, 0);
        sA = __builtin_amdgcn_mfma_f32_16x16x32_bf16(qaA1, kb1, sA, 0, 0, 0);
#pragma unroll
        for (int r = 0; r < 4; r++) svA[g][r] = sA[r];
      }
    }
    __builtin_amdgcn_s_setprio(0);
    if (kt == qtA && doA) {
#pragma unroll
      for (int g = 0; g < 4; g++)
#pragma unroll
        for (int r = 0; r < 4; r++) {
          int gi = iA + quad * 4 + r;
          int gj = k0 + g * 16 + l16;
          if (gj > gi) svA[g][r] = -__builtin_inff();
        }
    }
    if (kt == qtB) {
#pragma unroll
      for (int g = 0; g < 4; g++)
#pragma unroll
        for (int r = 0; r < 4; r++) {
          int gi = iB + quad * 4 + r;
          int gj = k0 + g * 16 + l16;
          if (gj > gi) svB[g][r] = -__builtin_inff();
        }
    }

    // ---- p = exp2(s) -> bf16 -> per-wave LDS (C->A layout) ----
    if (doA) {
#pragma unroll
      for (int g = 0; g < 4; g++)
#pragma unroll
        for (int r = 0; r < 4; r++)
          Ps[w][0][(quad * 4 + r) * 68 + g * 16 + l16] = truncbf(EXP2(svA[g][r]));
    }
#pragma unroll
    for (int g = 0; g < 4; g++)
#pragma unroll
      for (int r = 0; r < 4; r++)
        Ps[w][1][(quad * 4 + r) * 68 + g * 16 + l16] = truncbf(EXP2(svB[g][r]));

    // ---- y += P@V ; l += P@ones  (V frags shared across chains) ----
    __builtin_amdgcn_s_setprio(1);
#pragma unroll
    for (int kf = 0; kf < 2; kf++) {
      short8 vb[4];
#pragma unroll
      for (int g2 = 0; g2 < 4; g2++) {
        int row = g2 * 16 + l16;
        vb[g2] = *(const short8*)&Vs[cur][row * 64 + (((kf * 4 + quad) ^ (row & 7)) * 8)];
      }
      short8 paB = *(const short8*)&Ps[w][1][l16 * 68 + kf * 32 + quad * 8];
      acclB = __builtin_amdgcn_mfma_f32_16x16x32_bf16(paB, ones, acclB, 0, 0, 0);
#pragma unroll
      for (int g2 = 0; g2 < 4; g2++)
        accyB[g2] = __builtin_amdgcn_mfma_f32_16x16x32_bf16(paB, vb[g2], accyB[g2], 0, 0, 0);
      if (doA) {
        short8 paA = *(const short8*)&Ps[w][0][l16 * 68 + kf * 32 + quad * 8];
        acclA = __builtin_amdgcn_mfma_f32_16x16x32_bf16(paA, ones, acclA, 0, 0, 0);
#pragma unroll
        for (int g2 = 0; g2 < 4; g2++)
          accyA[g2] = __builtin_amdgcn_mfma_f32_16x16x32_bf16(paA, vb[g2], accyA[g2], 0, 0, 0);
      }
    }
    __builtin_amdgcn_s_setprio(0);

    // counted bottom wait: keep next-next tile's 4 loads in flight
    if (kt + 3 < nkt) {
      asm volatile("s_waitcnt vmcnt(4)" ::: "memory");
      __builtin_amdgcn_sched_barrier(0);
      __builtin_amdgcn_s_barrier();
    } else if (kt + 2 == nkt) {       // kt == nkt-2: drain the last tile
      asm volatile("s_waitcnt vmcnt(0)" ::: "memory");
      __builtin_amdgcn_sched_barrier(0);
      __builtin_amdgcn_s_barrier();
    } else if (kt + 3 == nkt) {       // kt == nkt-3: confirm tile nkt-2
      asm volatile("s_waitcnt vmcnt(4)" ::: "memory");
      __builtin_amdgcn_sched_barrier(0);
      __builtin_amdgcn_s_barrier();
    }
    // kt == nkt-1: no wait, fall through to epilogue
  }
#undef STAGE_KV
#undef GLOADA

  float invA[4], invB[4];
#pragma unroll
  for (int r = 0; r < 4; r++) {
    invA[r] = 1.0f / acclA[r];
    invB[r] = 1.0f / acclB[r];
  }
#pragma unroll
  for (int g2 = 0; g2 < 4; g2++) {
    int col = h * HEAD_DIM + g2 * 16 + l16;
#pragma unroll
    for (int r = 0; r < 4; r++) {
      int giA = iA + quad * 4 + r;
      int giB = iB + quad * 4 + r;
      Y[(rowb + giA) * N_EMBD + col] = f2bf(accyA[g2][r] * invA[r]);
      Y[(rowb + giB) * N_EMBD + col] = f2bf(accyB[g2][r] * invB[r]);
    }
  }
}

// ---------------------------------------------------------------------------
extern "C" void kernel_launch(void* const* d_in, const int* in_sizes, int n_in,
                              void* d_out, int out_size, void* d_ws, size_t ws_size,
                              hipStream_t stream) {
  (void)in_sizes; (void)n_in; (void)out_size; (void)ws_size;
  const void* x   = d_in[0];
  const void* Wsh = d_in[1];
  const void* bsh = d_in[2];
  const void* Wq  = d_in[3];
  const void* bq  = d_in[4];
  const void* Wk  = d_in[5];
  const void* bk  = d_in[6];
  const void* Wv  = d_in[7];
  const void* bv  = d_in[8];
  const void* Wo  = d_in[9];
  const void* bo  = d_in[10];

  char* wsb = (char*)d_ws;
  int* flag = (int*)wsb;
  u16* ws16 = (u16*)(wsb + 64);
  u16* Wcat = ws16;                                   // PNS*1024 (transposed)
  u16* bcat = Wcat + (size_t)PNS * N_EMBD;            // PNS
  u16* Woc  = bcat + PNS;                             // 1024*1024 (transposed)
  u16* boc  = Woc + (size_t)N_EMBD * N_EMBD;          // 1024
  u16* Pb   = boc + N_EMBD;                           // 8192*2816
  u16* Yb   = Pb + (size_t)M_ROWS * PNS;              // 8192*1024 (also Xb)
  u16* Vtb  = Yb + (size_t)M_ROWS * N_EMBD;           // 64*64*2048
  u16* Xb   = Yb;   // x->bf16 staging aliases Yb: proj reads Xb, attn writes Yb later

  detect_kernel<<<dim3(1), dim3(256), 0, stream>>>((const u16*)x, flag);
  pack_t_kernel<<<dim3(16, 16, 6), dim3(256), 0, stream>>>(
      Wsh, Wq, Wk, Wv, Wo, bsh, bq, bk, bv, bo, Wcat, Woc, bcat, boc, flag);
  xbf_kernel<<<dim3(M_ROWS * N_EMBD / (256 * 8)), dim3(256), 0, stream>>>(
      x, Xb, flag);
  // proj GEMM: [8192 x 2816] = Xb @ Wcat^T, bf16 out
  gemm8p_kernel<<<dim3(64 * (PNS / 256)), dim3(512), 0, stream>>>(
      Xb, Wcat, bcat, Pb, PNS, 64, flag, 0);
  vt_kernel<<<dim3(SEQ_T / 64, BATCH * N_HEADS), dim3(256), 0, stream>>>(
      Pb, Vtb);
  attn_kernel<<<dim3(BATCH * N_HEADS, NTILES / 2), dim3(256), 0, stream>>>(
      Pb, Vtb, Yb);
  // out GEMM: [8192 x 1024] = Yb @ Woc^T, f32 out when inputs were f32
  gemm8p_kernel<<<dim3(64 * (N_EMBD / 256)), dim3(512), 0, stream>>>(
      Yb, Woc, boc, d_out, N_EMBD, 64, flag, 1);
}